// Round 5
// baseline (18.795 us; speedup 1.0000x reference)
//
#include <hip/hip_runtime.h>
#include <math.h>

// ComparingLoss: s = sum_{i<j, disc(i,j)} (d_i + d_j), out = s/T
// s = sum_i d_i * c_i, canonical predicate (xi>xj)^(li>lj) over ALL j
// (valid both orientations for tie-free data; false at j==i).
//
// R5: ONE kernel. Finish via two-level packed-integer atomic tree:
//   level 1: 1024 blocks -> 32 cache lines, packed (fix<<6)|1; 32 arrivals
//            per line serialize only within a line (~0.4us, lines parallel).
//   level 2: each line's last arrival forwards its line subtotal to one
//            final line; its last arrival writes out[0].
// Integer adds are associative -> deterministic. Accumulators (2112 B)
// zeroed per call by one tiny hipMemsetAsync (capture-legal).

#define T_N    8192
#define BLK    256                  // threads per block
#define IPT    4                    // i-rows per thread
#define JC     64                   // j-chunk per block
#define NIB    (T_N / (BLK * IPT))  // 8 i-blocks
#define NJC    (T_N / JC)           // 128 j-chunks
#define NBLK   (NIB * NJC)          // 1024 blocks
#define NLINES 32                   // level-1 accumulator lines
#define ARR1   (NBLK / NLINES)      // 32 arrivals per line
#define FIXSCL 262144.0             // 2^18

typedef unsigned long long ull;

__global__ __launch_bounds__(BLK) void pair_count_kernel(
    const float* __restrict__ x, const float* __restrict__ lab,
    ull* __restrict__ acc, float* __restrict__ out) {
  __shared__ float2 js[JC];
  __shared__ float wsum[BLK / 64];

  const int tid = threadIdx.x;
  const int i0 = blockIdx.x * (BLK * IPT) + tid;  // rows i0 + k*BLK
  const int j0 = blockIdx.y * JC;

  if (tid < JC) js[tid] = make_float2(x[j0 + tid], lab[j0 + tid]);

  float xi[IPT], li[IPT];
#pragma unroll
  for (int k = 0; k < IPT; ++k) {
    xi[k] = x[i0 + k * BLK];
    li[k] = lab[i0 + k * BLK];
  }
  __syncthreads();

  int cnt[IPT] = {0, 0, 0, 0};
#pragma unroll 16
  for (int jj = 0; jj < JC; ++jj) {
    const float2 v = js[jj];  // broadcast ds_read_b64, conflict-free
#pragma unroll
    for (int k = 0; k < IPT; ++k)
      cnt[k] += (int)((xi[k] > v.x) != (li[k] > v.y));
  }

  float val = 0.f;
#pragma unroll
  for (int k = 0; k < IPT; ++k)
    val += fabsf(xi[k] - li[k]) * (float)cnt[k];

#pragma unroll
  for (int off = 32; off >= 1; off >>= 1) val += __shfl_down(val, off, 64);

  const int wave = tid >> 6;
  if ((tid & 63) == 0) wsum[wave] = val;
  __syncthreads();

  if (tid == 0) {
    const float s = wsum[0] + wsum[1] + wsum[2] + wsum[3];  // >= 0
    const ull fix = (ull)((double)s * FIXSCL + 0.5);
    const ull add = (fix << 6) | 1ULL;
    const int bid = blockIdx.y * NIB + blockIdx.x;
    const int line = bid & (NLINES - 1);
    // level-1 lines live at 64B stride: acc[line*8]; level-2 at acc[NLINES*8]
    const ull old = atomicAdd(&acc[line * 8], add);
    if ((old & 63ULL) == (ull)(ARR1 - 1)) {      // last arrival on this line
      const ull sub = (old + add) >> 6;          // line subtotal (fixed-pt)
      const ull add2 = (sub << 6) | 1ULL;
      const ull old2 = atomicAdd(&acc[NLINES * 8], add2);
      if ((old2 & 63ULL) == (ull)(NLINES - 1)) { // last line done
        const ull tot = (old2 + add2) >> 6;
        out[0] = (float)((double)tot * (1.0 / FIXSCL) / (double)T_N);
      }
    }
  }
}

extern "C" void kernel_launch(void* const* d_in, const int* in_sizes, int n_in,
                              void* d_out, int out_size, void* d_ws, size_t ws_size,
                              hipStream_t stream) {
  const float* x = (const float*)d_in[0];
  const float* lab = (const float*)d_in[1];
  float* out = (float*)d_out;
  ull* acc = (ull*)d_ws;

  hipMemsetAsync(d_ws, 0, (NLINES * 8 + 8) * sizeof(ull), stream);
  dim3 grid(NIB, NJC);
  pair_count_kernel<<<grid, BLK, 0, stream>>>(x, lab, acc, out);
}